// Round 11
// baseline (70.783 us; speedup 1.0000x reference)
//
#include <hip/hip_runtime.h>

// Multi-Scale Deformable Attention forward, fp32.
// B=1, Q=19947, heads=8, D=32, L=4, P=4.
// Levels: (100,150),(50,75),(25,38),(13,19); starts 0,15000,18750,19700.
//
// - Head-per-XCD: blockIdx.x%8 == head rides round-robin XCD dispatch;
//   per-head value slice (2.55 MB) resident in the XCD's 4 MiB L2
//   (verified R9/R10: FETCH_SIZE 315->57->30 MB).
// - Two-phase: phase 1 computes each (pair,sample)'s 4 masked bilinear
//   coefficients + 4 clamped token indices ONCE (512 items / 256 thr),
//   stores to LDS; phase 2 lanes read them broadcast (conflict-free
//   pad 17/12) and only gather + FMA. Removes the 8x redundant
//   metadata VALU work that bounded R10.

typedef float f32x4 __attribute__((ext_vector_type(4)));
typedef float f32x2 __attribute__((ext_vector_type(2)));
typedef int   i32x4 __attribute__((ext_vector_type(4)));

constexpr int HEADS = 8;
constexpr int DCH   = 32;
constexpr int LVLS  = 4;
constexpr int PTS   = 4;
constexpr int NSP   = LVLS * PTS;   // 16 samples per (q,h)
constexpr int NQ    = 19947;
constexpr int QPB   = 32;           // query pairs per block
constexpr int SPP   = 17;           // padded sample dim
constexpr int MW    = 12;           // words per meta item (4 coef + 4 idx + pad)

__global__ __launch_bounds__(256)
void msda_fwd_kernel(const float* __restrict__ value,
                     const float* __restrict__ loc,
                     const float* __restrict__ attw,
                     float* __restrict__ out)
{
    __shared__ __align__(16) float s_meta[QPB][SPP][MW];   // 25.5 KB

    const int h    = blockIdx.x & 7;          // head == XCD id
    const int qblk = blockIdx.x >> 3;
    const int q0   = qblk * QPB;
    const int t    = threadIdx.x;

    // ---------------- phase 1: metadata, one item per (pair,sample) ----------
#pragma unroll
    for (int it = 0; it < 2; ++it) {
        const int item = t + it * 256;        // 0..511
        const int pair = item >> 4;           // 0..31
        const int sp   = item & 15;           // 0..15
        const int q    = q0 + pair;
        if (q < NQ) {
            const size_t mb = (size_t)(q * HEADS + h);
            const f32x2 xy = __builtin_nontemporal_load(
                (const f32x2*)(loc + mb * (NSP * 2) + sp * 2));
            const float aw = __builtin_nontemporal_load(attw + mb * NSP + sp);

            const int l = sp >> 2;
            const float fW = (l == 0) ? 150.f : (l == 1) ? 75.f : (l == 2) ? 38.f : 19.f;
            const float fH = (l == 0) ? 100.f : (l == 1) ? 50.f : (l == 2) ? 25.f : 13.f;
            const int   W  = (l == 0) ? 150   : (l == 1) ? 75   : (l == 2) ? 38   : 19;
            const int   H  = (l == 0) ? 100   : (l == 1) ? 50   : (l == 2) ? 25   : 13;
            const int   S  = (l == 0) ? 0     : (l == 1) ? 15000: (l == 2) ? 18750: 19700;

            const float x = xy.x * fW - 0.5f;
            const float y = xy.y * fH - 0.5f;
            const float x0f = floorf(x);
            const float y0f = floorf(y);
            const float wx1 = x - x0f;
            const float wy1 = y - y0f;
            const float wx0 = 1.f - wx1;
            const float wy0 = 1.f - wy1;

            const int x0 = (int)x0f, y0 = (int)y0f;
            const int x1 = x0 + 1,   y1 = y0 + 1;

            const bool vx0 = (x0 >= 0) & (x0 < W);
            const bool vx1 = (x1 >= 0) & (x1 < W);
            const bool vy0 = (y0 >= 0) & (y0 < H);
            const bool vy1 = (y1 >= 0) & (y1 < H);

            const int cx0 = min(max(x0, 0), W - 1);
            const int cx1 = min(max(x1, 0), W - 1);
            const int cy0 = min(max(y0, 0), H - 1);
            const int cy1 = min(max(y1, 0), H - 1);

            float* m = &s_meta[pair][sp][0];
            m[0] = aw * wx0 * wy0 * ((vx0 && vy0) ? 1.f : 0.f);
            m[1] = aw * wx1 * wy0 * ((vx1 && vy0) ? 1.f : 0.f);
            m[2] = aw * wx0 * wy1 * ((vx0 && vy1) ? 1.f : 0.f);
            m[3] = aw * wx1 * wy1 * ((vx1 && vy1) ? 1.f : 0.f);
            int* mi = (int*)m;
            const int r0 = S + cy0 * W;
            const int r1 = S + cy1 * W;
            mi[4] = r0 + cx0;
            mi[5] = r0 + cx1;
            mi[6] = r1 + cx0;
            mi[7] = r1 + cx1;
        }
    }
    __syncthreads();

    // ---------------- phase 2: gather + accumulate ---------------------------
    const int sub = t >> 3;               // pair in block
    const int d0  = (t & 7) * 4;          // channel offset
    const int q   = q0 + sub;
    if (q >= NQ) return;

    // per-thread base pointer: value[token][h][d0..d0+3], token stride 256 floats
    const float* vptr = value + h * DCH + d0;

    float acc0 = 0.f, acc1 = 0.f, acc2 = 0.f, acc3 = 0.f;

#pragma unroll
    for (int sp = 0; sp < NSP; ++sp) {
        const f32x4 c  = *(const f32x4*)&s_meta[sub][sp][0];
        const i32x4 ix = *(const i32x4*)&s_meta[sub][sp][4];

        const f32x4 g00 = *(const f32x4*)(vptr + ((size_t)ix.x << 8));
        const f32x4 g01 = *(const f32x4*)(vptr + ((size_t)ix.y << 8));
        const f32x4 g10 = *(const f32x4*)(vptr + ((size_t)ix.z << 8));
        const f32x4 g11 = *(const f32x4*)(vptr + ((size_t)ix.w << 8));

        acc0 += c.x * g00.x + c.y * g01.x + c.z * g10.x + c.w * g11.x;
        acc1 += c.x * g00.y + c.y * g01.y + c.z * g10.y + c.w * g11.y;
        acc2 += c.x * g00.z + c.y * g01.z + c.z * g10.z + c.w * g11.z;
        acc3 += c.x * g00.w + c.y * g01.w + c.z * g10.w + c.w * g11.w;
    }

    f32x4 r;
    r.x = acc0; r.y = acc1; r.z = acc2; r.w = acc3;
    __builtin_nontemporal_store(r, (f32x4*)(out + (size_t)(q * HEADS + h) * DCH + d0));
}

extern "C" void kernel_launch(void* const* d_in, const int* in_sizes, int n_in,
                              void* d_out, int out_size, void* d_ws, size_t ws_size,
                              hipStream_t stream) {
    const float* value = (const float*)d_in[0];
    const float* loc   = (const float*)d_in[3];
    const float* attw  = (const float*)d_in[4];
    float* out = (float*)d_out;

    const int qblocks = (NQ + QPB - 1) / QPB;    // 624
    const int grid = qblocks * HEADS;            // 4992
    msda_fwd_kernel<<<grid, 256, 0, stream>>>(value, loc, attw, out);
}